// Round 1
// baseline (3566.274 us; speedup 1.0000x reference)
//
#include <hip/hip_runtime.h>
#include <hip/hip_bf16.h>

typedef unsigned short u16;
typedef unsigned int   u32;
typedef __attribute__((ext_vector_type(8))) short short8;   // 8 x bf16 (4 VGPRs)
typedef __attribute__((ext_vector_type(4))) float f32x4;

#define DEVINL static __device__ __forceinline__

// round-to-nearest-even f32 -> bf16 (values are finite, no NaN path needed)
DEVINL u16 f2bf(float x) {
  u32 u = __float_as_uint(x);
  u32 r = (u + 0x7fffu + ((u >> 16) & 1u)) >> 16;
  return (u16)r;
}

// async global->LDS, 16B per lane. LDS dest is wave-uniform base + lane*16.
#define GLD16(gp, lp) __builtin_amdgcn_global_load_lds(                     \
    (const __attribute__((address_space(1))) u32*)(gp),                     \
    (__attribute__((address_space(3))) u32*)(lp), 16, 0, 0)

// ---------------------------------------------------------------------------
// fp32 -> bf16 bulk convert (n4 = n/4 float4 chunks)
__global__ __launch_bounds__(256) void conv_kernel(const float* __restrict__ s,
                                                   u16* __restrict__ d, int n4) {
  int i = blockIdx.x * 256 + threadIdx.x;
  if (i < n4) {
    float4 v = ((const float4*)s)[i];
    ushort4 o;
    o.x = f2bf(v.x); o.y = f2bf(v.y); o.z = f2bf(v.z); o.w = f2bf(v.w);
    ((ushort4*)d)[i] = o;
  }
}

// cond_e gather + fused bias vectors (bih+bhh)
__global__ __launch_bounds__(256) void prep_small(
    const int* __restrict__ cond, const float* __restrict__ emb_cond,
    const float* __restrict__ bihN, const float* __restrict__ bhhN,
    const float* __restrict__ bihD, const float* __restrict__ bhhD,
    float* __restrict__ ce, float* __restrict__ biasN, float* __restrict__ biasD) {
  int tid = blockIdx.x * 256 + threadIdx.x;
  if (tid < 512) {                       // 64 x 8 cond embedding
    int b = tid >> 3, j = tid & 7;
    ce[tid] = emb_cond[cond[b] * 8 + j];
  }
  int i = tid - 512;
  if (i >= 0 && i < 4096) {
    biasN[i] = bihN[i] + bhhN[i];
    biasD[i] = bihD[i] + bhhD[i];
  }
}

// encoder h0 = [zeros(B,1016), cond_e], c0 = 0
__global__ __launch_bounds__(256) void init_enc(const float* __restrict__ ce,
                                                float* __restrict__ hf0,
                                                u16* __restrict__ hb0,
                                                float* __restrict__ c) {
  int tid = blockIdx.x * 256 + threadIdx.x;   // 64*1024
  int b = tid >> 10, col = tid & 1023;
  float v = (col >= 1016) ? ce[b * 8 + (col - 1016)] : 0.f;
  hf0[tid] = v;
  hb0[tid] = f2bf(v);
  c[tid] = 0.f;
}

// embedding row gather -> bf16, X[t*64+b][1024]
__global__ __launch_bounds__(256) void gather_kernel(const float* __restrict__ emb,
                                                     const int* __restrict__ words,
                                                     u16* __restrict__ X, int dec) {
  int r = blockIdx.x;                    // r = t*64 + b
  int t = r >> 6, b = r & 63;
  int tok = dec ? ((t == 0) ? 0 : words[b * 64 + t - 1]) : words[b * 64 + t];
  float4 v = ((const float4*)(emb + (size_t)tok * 1024))[threadIdx.x];
  ushort4 o;
  o.x = f2bf(v.x); o.y = f2bf(v.y); o.z = f2bf(v.z); o.w = f2bf(v.w);
  ((ushort4*)(X + (size_t)r * 1024))[threadIdx.x] = o;
}

// ---------------------------------------------------------------------------
// C = A(MxK) * B(NxK)^T + bias, bf16 inputs, fp32 out. 128x128 tile, BK=32,
// 4 waves 2x2, global_load_lds staging (m97 structure).
// REMAP: row r=(t*64+b) is written to out[b][t][:] (logits transpose).
template <bool REMAP>
__global__ __launch_bounds__(256) void gemm_bt_kernel(
    const u16* __restrict__ A, const u16* __restrict__ B,
    float* __restrict__ C, const float* __restrict__ bias, int N, int K) {
  __shared__ u16 lA[128 * 32];
  __shared__ u16 lB[128 * 32];
  const int tid = threadIdx.x;
  const int lane = tid & 63;
  const int wid = tid >> 6;
  const int tile_m = blockIdx.y * 128;
  const int tile_n = blockIdx.x * 128;
  const int wm = wid >> 1, wn = wid & 1;

  const int ldr = lane >> 2;         // row within 16-row chunk
  const int lko = (lane & 3) * 8;    // k element offset of this lane's 16B

  f32x4 acc[4][4];
#pragma unroll
  for (int i = 0; i < 4; ++i)
#pragma unroll
    for (int j = 0; j < 4; ++j) acc[i][j] = (f32x4)0.f;

  const size_t aBase = (size_t)tile_m * K;
  const size_t bBase = (size_t)tile_n * K;

  for (int k0 = 0; k0 < K; k0 += 32) {
    __syncthreads();
#pragma unroll
    for (int q = 0; q < 2; ++q) {
      int ch = wid * 2 + q;                    // chunk 0..7, 16 rows each
      int row = ch * 16 + ldr;
      GLD16(A + aBase + (size_t)row * K + k0 + lko, &lA[ch * 512]);
      GLD16(B + bBase + (size_t)row * K + k0 + lko, &lB[ch * 512]);
    }
    __syncthreads();
    short8 af[4], bf[4];
#pragma unroll
    for (int i = 0; i < 4; ++i)
      af[i] = *(const short8*)&lA[(wm * 64 + i * 16 + (lane & 15)) * 32 + (lane >> 4) * 8];
#pragma unroll
    for (int j = 0; j < 4; ++j)
      bf[j] = *(const short8*)&lB[(wn * 64 + j * 16 + (lane & 15)) * 32 + (lane >> 4) * 8];
#pragma unroll
    for (int i = 0; i < 4; ++i)
#pragma unroll
      for (int j = 0; j < 4; ++j)
        acc[i][j] = __builtin_amdgcn_mfma_f32_16x16x32_bf16(af[i], bf[j], acc[i][j], 0, 0, 0);
  }

#pragma unroll
  for (int i = 0; i < 4; ++i) {
    int row0 = tile_m + wm * 64 + i * 16 + ((lane >> 4) << 2);
#pragma unroll
    for (int j = 0; j < 4; ++j) {
      int col = tile_n + wn * 64 + j * 16 + (lane & 15);
      float bv = bias ? bias[col] : 0.f;
#pragma unroll
      for (int e = 0; e < 4; ++e) {
        int r = row0 + e;
        size_t o;
        if (REMAP) o = (size_t)((r & 63) * 64 + (r >> 6)) * (size_t)N + col;
        else       o = (size_t)r * (size_t)N + col;
        C[o] = acc[i][j][e] + bv;
      }
    }
  }
}

// ---------------------------------------------------------------------------
// One LSTM time step, fused gates-GEMM + cell update.
// gates[64,4096] = Xp[t] + h @ Whh^T ; i,f,g,o = split(gates)
// Grid: 64 WGs x 256 thr. WG owns 16 h-columns; wave w computes gate group w.
__global__ __launch_bounds__(256) void lstm_step_kernel(
    const u16* __restrict__ hb,    // h_t bf16 [64][1024]
    const u16* __restrict__ Whh,   // bf16 [4096][1024]
    const float* __restrict__ Xp,  // fp32 [4096][4096] (x@Wih^T + bih + bhh)
    float* __restrict__ c,         // fp32 [64][1024], in-place
    u16* __restrict__ hb_n, float* __restrict__ hf_n,
    u16* __restrict__ hs_out,      // decoder: hs_d + t*65536, else null
    int t) {
  __shared__ float lg[4][64][16];
  const int tid = threadIdx.x;
  const int lane = tid & 63;
  const int wid = tid >> 6;
  const int hc0 = blockIdx.x * 16;
  const int l15 = lane & 15;
  const int kof = (lane >> 4) * 8;

  f32x4 acc[4];
#pragma unroll
  for (int i = 0; i < 4; ++i) acc[i] = (f32x4)0.f;

  const u16* Brow = Whh + (size_t)(wid * 1024 + hc0 + l15) * 1024 + kof;
  const u16* Arow = hb + (size_t)l15 * 1024 + kof;
  for (int kk = 0; kk < 32; ++kk) {
    short8 b = *(const short8*)(Brow + kk * 32);
#pragma unroll
    for (int mi = 0; mi < 4; ++mi) {
      short8 a = *(const short8*)(Arow + mi * 16384 + kk * 32);
      acc[mi] = __builtin_amdgcn_mfma_f32_16x16x32_bf16(a, b, acc[mi], 0, 0, 0);
    }
  }
#pragma unroll
  for (int mi = 0; mi < 4; ++mi) {
    int m = mi * 16 + (lane >> 4) * 4;
#pragma unroll
    for (int e = 0; e < 4; ++e) lg[wid][m + e][l15] = acc[mi][e];
  }
  __syncthreads();

#pragma unroll
  for (int it = 0; it < 4; ++it) {
    int idx = tid + it * 256;           // 1024 cells
    int b = idx >> 4, n = idx & 15;
    int col = hc0 + n;
    size_t xrow = (size_t)(t * 64 + b) * 4096;
    float gi = lg[0][b][n] + Xp[xrow + col];
    float gf = lg[1][b][n] + Xp[xrow + 1024 + col];
    float gg = lg[2][b][n] + Xp[xrow + 2048 + col];
    float go = lg[3][b][n] + Xp[xrow + 3072 + col];
    float si = 1.f / (1.f + __expf(-gi));
    float sf = 1.f / (1.f + __expf(-gf));
    float so = 1.f / (1.f + __expf(-go));
    float tg = tanhf(gg);
    int ci = b * 1024 + col;
    float cn = sf * c[ci] + si * tg;
    float hn = so * tanhf(cn);
    c[ci] = cn;
    hb_n[ci] = f2bf(hn);
    hf_n[ci] = hn;
    if (hs_out) hs_out[ci] = f2bf(hn);
  }
}

// ---------------------------------------------------------------------------
// mean/logvar/latent + hd0 = [latent|cond_e] @ W_st^T + b_st. One block per batch.
// NOTE: hT may alias hf0 (block b reads only row b fully before writing it).
__global__ __launch_bounds__(256) void latent_hd0_kernel(
    const float* hT, const float* Wm, const float* bm,
    const float* Wl, const float* bl, const float* Wst, const float* bst,
    const float* eps, const float* ce,
    float* hf0, u16* hb0, float* c) {
  __shared__ float red[64][4];
  __shared__ float ml[64];
  __shared__ float lat[40];
  int b = blockIdx.x;
  int tid = threadIdx.x;
  int o = tid >> 2, p = tid & 3;
  const float* w = (o < 32) ? (Wm + (size_t)o * 1024) : (Wl + (size_t)(o - 32) * 1024);
  const float* h = hT + (size_t)b * 1024;
  float s = 0.f;
  for (int k = p * 256; k < p * 256 + 256; ++k) s += h[k] * w[k];
  red[o][p] = s;
  __syncthreads();
  if (tid < 64) {
    float v = red[tid][0] + red[tid][1] + red[tid][2] + red[tid][3];
    v += (tid < 32) ? bm[tid] : bl[tid - 32];
    ml[tid] = v;
  }
  __syncthreads();
  if (tid < 32) lat[tid] = eps[b * 32 + tid] * __expf(0.5f * ml[32 + tid]) + ml[tid];
  if (tid >= 32 && tid < 40) lat[tid] = ce[b * 8 + (tid - 32)];
  __syncthreads();
  for (int hc = tid; hc < 1024; hc += 256) {
    float s2 = bst[hc];
    const float* wr = Wst + (size_t)hc * 40;
#pragma unroll
    for (int j = 0; j < 40; ++j) s2 += lat[j] * wr[j];
    int i = b * 1024 + hc;
    hf0[i] = s2;
    hb0[i] = f2bf(s2);
    c[i] = 0.f;
  }
}

// ---------------------------------------------------------------------------
extern "C" void kernel_launch(void* const* d_in, const int* in_sizes, int n_in,
                              void* d_out, int out_size, void* d_ws, size_t ws_size,
                              hipStream_t stream) {
  const int*   input_word = (const int*)d_in[0];
  const int*   cond       = (const int*)d_in[1];
  const float* emb_N      = (const float*)d_in[2];
  const float* Wih_N      = (const float*)d_in[3];
  const float* Whh_N      = (const float*)d_in[4];
  const float* bih_N      = (const float*)d_in[5];
  const float* bhh_N      = (const float*)d_in[6];
  const float* emb_D      = (const float*)d_in[7];
  const float* Wih_D      = (const float*)d_in[8];
  const float* Whh_D      = (const float*)d_in[9];
  const float* bih_D      = (const float*)d_in[10];
  const float* bhh_D      = (const float*)d_in[11];
  const float* emb_cond   = (const float*)d_in[12];
  const float* W_mean     = (const float*)d_in[13];
  const float* b_mean     = (const float*)d_in[14];
  const float* W_logvar   = (const float*)d_in[15];
  const float* b_logvar   = (const float*)d_in[16];
  const float* W_st       = (const float*)d_in[17];
  const float* b_st       = (const float*)d_in[18];
  const float* W_out      = (const float*)d_in[19];
  const float* b_out      = (const float*)d_in[20];
  const float* eps        = (const float*)d_in[21];
  float* out = (float*)d_out;

  char* ws = (char*)d_ws;
  size_t off = 0;
  auto alloc = [&](size_t b) { size_t p = off; off += (b + 255) & ~(size_t)255; return p; };
  u16*   wihN = (u16*)(ws + alloc(4096ull * 1024 * 2));
  u16*   whhN = (u16*)(ws + alloc(4096ull * 1024 * 2));
  u16*   wihD = (u16*)(ws + alloc(4096ull * 1024 * 2));
  u16*   whhD = (u16*)(ws + alloc(4096ull * 1024 * 2));
  u16*   wout = (u16*)(ws + alloc(32000ull * 1024 * 2));
  u16*   Xe   = (u16*)(ws + alloc(4096ull * 1024 * 2));
  u16*   Xd   = (u16*)(ws + alloc(4096ull * 1024 * 2));
  float* Xp   = (float*)(ws + alloc(4096ull * 4096 * 4));   // reused enc then dec
  u16*   hsd  = (u16*)(ws + alloc(4096ull * 1024 * 2));
  u16*   hb   = (u16*)(ws + alloc(2ull * 64 * 1024 * 2));   // bf16 h, dbuf
  float* hf   = (float*)(ws + alloc(2ull * 64 * 1024 * 4)); // fp32 h, dbuf
  float* cbuf = (float*)(ws + alloc(64ull * 1024 * 4));
  float* biasN = (float*)(ws + alloc(4096 * 4));
  float* biasD = (float*)(ws + alloc(4096 * 4));
  float* ce    = (float*)(ws + alloc(64 * 8 * 4));
  if (off > ws_size) return;   // workspace too small — fail cleanly

  // weight conversions (independent)
  conv_kernel<<<4096, 256, 0, stream>>>(Wih_N, wihN, 1048576);
  conv_kernel<<<4096, 256, 0, stream>>>(Whh_N, whhN, 1048576);
  conv_kernel<<<4096, 256, 0, stream>>>(Wih_D, wihD, 1048576);
  conv_kernel<<<4096, 256, 0, stream>>>(Whh_D, whhD, 1048576);
  conv_kernel<<<32000, 256, 0, stream>>>(W_out, wout, 8192000);
  prep_small<<<18, 256, 0, stream>>>(cond, emb_cond, bih_N, bhh_N, bih_D, bhh_D,
                                     ce, biasN, biasD);
  gather_kernel<<<4096, 256, 0, stream>>>(emb_N, input_word, Xe, 0);
  gather_kernel<<<4096, 256, 0, stream>>>(emb_D, input_word, Xd, 1);
  init_enc<<<256, 256, 0, stream>>>(ce, hf, hb, cbuf);

  // encoder: Xp = X_enc @ Wih_N^T + (bih+bhh)
  gemm_bt_kernel<false><<<dim3(32, 32), 256, 0, stream>>>(Xe, wihN, Xp, biasN, 4096, 1024);
  for (int t = 0; t < 64; ++t) {
    u16*   hcur = hb + (size_t)(t & 1) * 65536;
    u16*   hnxt = hb + (size_t)((t + 1) & 1) * 65536;
    float* hfn  = hf + (size_t)((t + 1) & 1) * 65536;
    lstm_step_kernel<<<64, 256, 0, stream>>>(hcur, whhN, Xp, cbuf, hnxt, hfn, nullptr, t);
  }
  // latent + decoder init (h_T is in fp32 buffer 0; hd0 written back to buffer 0)
  latent_hd0_kernel<<<64, 256, 0, stream>>>(hf, W_mean, b_mean, W_logvar, b_logvar,
                                            W_st, b_st, eps, ce, hf, hb, cbuf);
  // decoder
  gemm_bt_kernel<false><<<dim3(32, 32), 256, 0, stream>>>(Xd, wihD, Xp, biasD, 4096, 1024);
  for (int t = 0; t < 64; ++t) {
    u16*   hcur = hb + (size_t)(t & 1) * 65536;
    u16*   hnxt = hb + (size_t)((t + 1) & 1) * 65536;
    float* hfn  = hf + (size_t)((t + 1) & 1) * 65536;
    lstm_step_kernel<<<64, 256, 0, stream>>>(hcur, whhD, Xp, cbuf, hnxt, hfn,
                                             hsd + (size_t)t * 65536, t);
  }
  // logits = hs_d @ W_out^T + b_out, remapped [t,b,:] -> [b,t,:]
  gemm_bt_kernel<true><<<dim3(250, 32), 256, 0, stream>>>(hsd, wout, out, b_out, 32000, 1024);
}

// Round 5
// 1938.168 us; speedup vs baseline: 1.8400x; 1.8400x over previous
//
#include <hip/hip_runtime.h>
#include <hip/hip_bf16.h>

typedef unsigned short u16;
typedef unsigned int   u32;
typedef __attribute__((ext_vector_type(8))) short short8;   // 8 x bf16 (4 VGPRs)
typedef __attribute__((ext_vector_type(4))) float f32x4;

#define DEVINL static __device__ __forceinline__

// round-to-nearest-even f32 -> bf16
DEVINL u16 f2bf(float x) {
  u32 u = __float_as_uint(x);
  u32 r = (u + 0x7fffu + ((u >> 16) & 1u)) >> 16;
  return (u16)r;
}

// async global->LDS, 16B per lane (GEMM). LDS dest = uniform base + lane*16.
#define GLD16(gp, lp) __builtin_amdgcn_global_load_lds(                     \
    (const __attribute__((address_space(1))) u32*)(gp),                     \
    (__attribute__((address_space(3))) u32*)(lp), 16, 0, 0)

// ---------------------------------------------------------------------------
// fp32 -> bf16 bulk convert (n4 = n/4 float4 chunks)
__global__ __launch_bounds__(256) void conv_kernel(const float* __restrict__ s,
                                                   u16* __restrict__ d, int n4) {
  int i = blockIdx.x * 256 + threadIdx.x;
  if (i < n4) {
    float4 v = ((const float4*)s)[i];
    ushort4 o;
    o.x = f2bf(v.x); o.y = f2bf(v.y); o.z = f2bf(v.z); o.w = f2bf(v.w);
    ((ushort4*)d)[i] = o;
  }
}

// cond_e gather + fused bias vectors (bih+bhh)
__global__ __launch_bounds__(256) void prep_small(
    const int* __restrict__ cond, const float* __restrict__ emb_cond,
    const float* __restrict__ bihN, const float* __restrict__ bhhN,
    const float* __restrict__ bihD, const float* __restrict__ bhhD,
    float* __restrict__ ce, float* __restrict__ biasN, float* __restrict__ biasD) {
  int tid = blockIdx.x * 256 + threadIdx.x;
  if (tid < 512) {
    int b = tid >> 3, j = tid & 7;
    ce[tid] = emb_cond[cond[b] * 8 + j];
  }
  int i = tid - 512;
  if (i >= 0 && i < 4096) {
    biasN[i] = bihN[i] + bhhN[i];
    biasD[i] = bihD[i] + bhhD[i];
  }
}

// encoder h0 = [zeros(B,1016), cond_e] -> bf16 into hbuf[0]; c0 = 0
__global__ __launch_bounds__(256) void init_enc(const float* __restrict__ ce,
                                                u16* __restrict__ hb0,
                                                float* __restrict__ c) {
  int tid = blockIdx.x * 256 + threadIdx.x;   // 64*1024
  int b = tid >> 10, col = tid & 1023;
  float v = (col >= 1016) ? ce[b * 8 + (col - 1016)] : 0.f;
  hb0[tid] = f2bf(v);
  c[tid] = 0.f;
}

// embedding row gather -> bf16, X[t*64+b][1024]
__global__ __launch_bounds__(256) void gather_kernel(const float* __restrict__ emb,
                                                     const int* __restrict__ words,
                                                     u16* __restrict__ X, int dec) {
  int r = blockIdx.x;                    // r = t*64 + b
  int t = r >> 6, b = r & 63;
  int tok = dec ? ((t == 0) ? 0 : words[b * 64 + t - 1]) : words[b * 64 + t];
  float4 v = ((const float4*)(emb + (size_t)tok * 1024))[threadIdx.x];
  ushort4 o;
  o.x = f2bf(v.x); o.y = f2bf(v.y); o.z = f2bf(v.z); o.w = f2bf(v.w);
  ((ushort4*)(X + (size_t)r * 1024))[threadIdx.x] = o;
}

// ---------------------------------------------------------------------------
// C = A(MxK) * B(NxK)^T + bias, bf16 in, fp32 out. 128x128 tile, BK=32.
// REMAP: row r=(t*64+b) written to out[b][t][:] with nontemporal stores
// (512MB streaming write must not evict L3-resident W_out).
template <bool REMAP>
__global__ __launch_bounds__(256) void gemm_bt_kernel(
    const u16* __restrict__ A, const u16* __restrict__ B,
    float* __restrict__ C, const float* __restrict__ bias, int N, int K) {
  __shared__ u16 lA[128 * 32];
  __shared__ u16 lB[128 * 32];
  const int tid = threadIdx.x;
  const int lane = tid & 63;
  const int wid = tid >> 6;
  const int tile_m = blockIdx.y * 128;
  const int tile_n = blockIdx.x * 128;
  const int wm = wid >> 1, wn = wid & 1;

  const int ldr = lane >> 2;
  const int lko = (lane & 3) * 8;

  f32x4 acc[4][4];
#pragma unroll
  for (int i = 0; i < 4; ++i)
#pragma unroll
    for (int j = 0; j < 4; ++j) acc[i][j] = (f32x4)0.f;

  const size_t aBase = (size_t)tile_m * K;
  const size_t bBase = (size_t)tile_n * K;

  for (int k0 = 0; k0 < K; k0 += 32) {
    __syncthreads();
#pragma unroll
    for (int q = 0; q < 2; ++q) {
      int ch = wid * 2 + q;
      int row = ch * 16 + ldr;
      GLD16(A + aBase + (size_t)row * K + k0 + lko, &lA[ch * 512]);
      GLD16(B + bBase + (size_t)row * K + k0 + lko, &lB[ch * 512]);
    }
    __syncthreads();
    short8 af[4], bf[4];
#pragma unroll
    for (int i = 0; i < 4; ++i)
      af[i] = *(const short8*)&lA[(wm * 64 + i * 16 + (lane & 15)) * 32 + (lane >> 4) * 8];
#pragma unroll
    for (int j = 0; j < 4; ++j)
      bf[j] = *(const short8*)&lB[(wn * 64 + j * 16 + (lane & 15)) * 32 + (lane >> 4) * 8];
#pragma unroll
    for (int i = 0; i < 4; ++i)
#pragma unroll
      for (int j = 0; j < 4; ++j)
        acc[i][j] = __builtin_amdgcn_mfma_f32_16x16x32_bf16(af[i], bf[j], acc[i][j], 0, 0, 0);
  }

#pragma unroll
  for (int i = 0; i < 4; ++i) {
    int row0 = tile_m + wm * 64 + i * 16 + ((lane >> 4) << 2);
#pragma unroll
    for (int j = 0; j < 4; ++j) {
      int col = tile_n + wn * 64 + j * 16 + (lane & 15);
      float bv = bias ? bias[col] : 0.f;
#pragma unroll
      for (int e = 0; e < 4; ++e) {
        int r = row0 + e;
        float v = acc[i][j][e] + bv;
        if (REMAP) {
          size_t o = (size_t)((r & 63) * 64 + (r >> 6)) * (size_t)N + col;
          __builtin_nontemporal_store(v, &C[o]);
        } else {
          C[(size_t)r * (size_t)N + col] = v;
        }
      }
    }
  }
}

// ---------------------------------------------------------------------------
// One LSTM step, 256 WGs (64 col-groups x 4 batch-groups) x 256 threads.
// WG (cg,bg): h-cols [cg*16,cg*16+16), batches [bg*16,bg*16+16).
// Wave wid = gate. 32 MFMAs/wave over K=1024, 4 independent acc chains.
// Cross-step data via kernel boundaries (proven-coherent).
__global__ __launch_bounds__(256) void lstm_step2(
    const u16* __restrict__ hb,    // h_t bf16 [64][1024]
    const u16* __restrict__ Whh,   // bf16 [4096][1024]
    const float* __restrict__ Xp,  // fp32 [4096][4096] (x@Wih^T + bih + bhh)
    float* __restrict__ c,         // fp32 [64][1024], in-place
    u16* __restrict__ hb_n,        // h_{t+1} bf16
    u16* __restrict__ hs_out,      // decoder: hsd + t*65536, else null
    float* __restrict__ hT_out,    // encoder t==63: fp32 h_T, else null
    int t) {
  __shared__ float lg[4][16][16];  // [gate][batch][col]
  const int tid = threadIdx.x;
  const int lane = tid & 63;
  const int wid = tid >> 6;        // gate
  const int cg = blockIdx.x >> 2;
  const int bg = blockIdx.x & 3;
  const int hc0 = cg * 16;
  const int b0 = bg * 16;
  const int l15 = lane & 15;
  const int kof = (lane >> 4) * 8;

  f32x4 acc[4];
#pragma unroll
  for (int i = 0; i < 4; ++i) acc[i] = (f32x4)0.f;

  const u16* Brow = Whh + (size_t)(wid * 1024 + hc0 + l15) * 1024 + kof;
  const u16* Arow = hb + (size_t)(b0 + l15) * 1024 + kof;
#pragma unroll
  for (int kk = 0; kk < 32; ++kk) {
    short8 bfr = *(const short8*)(Brow + kk * 32);
    short8 a   = *(const short8*)(Arow + kk * 32);
    acc[kk & 3] = __builtin_amdgcn_mfma_f32_16x16x32_bf16(a, bfr, acc[kk & 3], 0, 0, 0);
  }
  // sum the 4 chains
  f32x4 asum = acc[0] + acc[1] + acc[2] + acc[3];
  {
    int m = (lane >> 4) * 4;
#pragma unroll
    for (int e = 0; e < 4; ++e) lg[wid][m + e][l15] = asum[e];
  }
  __syncthreads();

  // cell update: 1 cell per thread
  int bb = tid >> 4, n = tid & 15;
  int b = b0 + bb, col = hc0 + n;
  size_t xrow = (size_t)(t * 64 + b) * 4096 + col;
  float gi = lg[0][bb][n] + Xp[xrow];
  float gf = lg[1][bb][n] + Xp[xrow + 1024];
  float gg = lg[2][bb][n] + Xp[xrow + 2048];
  float go = lg[3][bb][n] + Xp[xrow + 3072];
  float si = 1.f / (1.f + __expf(-gi));
  float sf = 1.f / (1.f + __expf(-gf));
  float so = 1.f / (1.f + __expf(-go));
  float tg = tanhf(gg);
  int ci = b * 1024 + col;
  float cn = sf * c[ci] + si * tg;
  float hn = so * tanhf(cn);
  c[ci] = cn;
  u16 h16 = f2bf(hn);
  hb_n[ci] = h16;
  if (hs_out) hs_out[ci] = h16;
  if (hT_out) hT_out[ci] = hn;
}

// ---------------------------------------------------------------------------
// mean/logvar/latent + hd0 = [latent|cond_e] @ W_st^T + b_st -> bf16 h0; c=0.
__global__ __launch_bounds__(256) void latent_hd0_kernel(
    const float* hT, const float* Wm, const float* bm,
    const float* Wl, const float* bl, const float* Wst, const float* bst,
    const float* eps, const float* ce, u16* hb0, float* c) {
  __shared__ float red[64][4];
  __shared__ float ml[64];
  __shared__ float lat[40];
  int b = blockIdx.x;
  int tid = threadIdx.x;
  int o = tid >> 2, p = tid & 3;
  const float* w = (o < 32) ? (Wm + (size_t)o * 1024) : (Wl + (size_t)(o - 32) * 1024);
  const float* h = hT + (size_t)b * 1024;
  float s = 0.f;
  for (int k = p * 256; k < p * 256 + 256; ++k) s += h[k] * w[k];
  red[o][p] = s;
  __syncthreads();
  if (tid < 64) {
    float v = red[tid][0] + red[tid][1] + red[tid][2] + red[tid][3];
    v += (tid < 32) ? bm[tid] : bl[tid - 32];
    ml[tid] = v;
  }
  __syncthreads();
  if (tid < 32) lat[tid] = eps[b * 32 + tid] * __expf(0.5f * ml[32 + tid]) + ml[tid];
  if (tid >= 32 && tid < 40) lat[tid] = ce[b * 8 + (tid - 32)];
  __syncthreads();
  for (int hc = tid; hc < 1024; hc += 256) {
    float s2 = bst[hc];
    const float* wr = Wst + (size_t)hc * 40;
#pragma unroll
    for (int j = 0; j < 40; ++j) s2 += lat[j] * wr[j];
    int i = b * 1024 + hc;
    hb0[i] = f2bf(s2);
    c[i] = 0.f;
  }
}

// ---------------------------------------------------------------------------
extern "C" void kernel_launch(void* const* d_in, const int* in_sizes, int n_in,
                              void* d_out, int out_size, void* d_ws, size_t ws_size,
                              hipStream_t stream) {
  const int*   input_word = (const int*)d_in[0];
  const int*   cond       = (const int*)d_in[1];
  const float* emb_N      = (const float*)d_in[2];
  const float* Wih_N      = (const float*)d_in[3];
  const float* Whh_N      = (const float*)d_in[4];
  const float* bih_N      = (const float*)d_in[5];
  const float* bhh_N      = (const float*)d_in[6];
  const float* emb_D      = (const float*)d_in[7];
  const float* Wih_D      = (const float*)d_in[8];
  const float* Whh_D      = (const float*)d_in[9];
  const float* bih_D      = (const float*)d_in[10];
  const float* bhh_D      = (const float*)d_in[11];
  const float* emb_cond   = (const float*)d_in[12];
  const float* W_mean     = (const float*)d_in[13];
  const float* b_mean     = (const float*)d_in[14];
  const float* W_logvar   = (const float*)d_in[15];
  const float* b_logvar   = (const float*)d_in[16];
  const float* W_st       = (const float*)d_in[17];
  const float* b_st       = (const float*)d_in[18];
  const float* W_out      = (const float*)d_in[19];
  const float* b_out      = (const float*)d_in[20];
  const float* eps        = (const float*)d_in[21];
  float* out = (float*)d_out;

  char* ws = (char*)d_ws;
  size_t off = 0;
  auto alloc = [&](size_t b) { size_t p = off; off += (b + 255) & ~(size_t)255; return p; };
  u16*   wihN = (u16*)(ws + alloc(4096ull * 1024 * 2));
  u16*   whhN = (u16*)(ws + alloc(4096ull * 1024 * 2));
  u16*   wihD = (u16*)(ws + alloc(4096ull * 1024 * 2));
  u16*   whhD = (u16*)(ws + alloc(4096ull * 1024 * 2));
  u16*   wout = (u16*)(ws + alloc(32000ull * 1024 * 2));
  u16*   Xe   = (u16*)(ws + alloc(4096ull * 1024 * 2));
  u16*   Xd   = (u16*)(ws + alloc(4096ull * 1024 * 2));
  float* Xp   = (float*)(ws + alloc(4096ull * 4096 * 4));   // enc then dec
  u16*   hsd  = (u16*)(ws + alloc(4096ull * 1024 * 2));
  u16*   hb   = (u16*)(ws + alloc(2ull * 64 * 1024 * 2));   // bf16 h dbuf
  float* hf   = (float*)(ws + alloc(64ull * 1024 * 4));     // fp32 h_T (encoder)
  float* cbuf = (float*)(ws + alloc(64ull * 1024 * 4));     // fp32 cell state
  float* biasN = (float*)(ws + alloc(4096 * 4));
  float* biasD = (float*)(ws + alloc(4096 * 4));
  float* ce    = (float*)(ws + alloc(64 * 8 * 4));
  if (off > ws_size) return;

  conv_kernel<<<4096, 256, 0, stream>>>(Wih_N, wihN, 1048576);
  conv_kernel<<<4096, 256, 0, stream>>>(Whh_N, whhN, 1048576);
  conv_kernel<<<4096, 256, 0, stream>>>(Wih_D, wihD, 1048576);
  conv_kernel<<<4096, 256, 0, stream>>>(Whh_D, whhD, 1048576);
  conv_kernel<<<32000, 256, 0, stream>>>(W_out, wout, 8192000);
  prep_small<<<18, 256, 0, stream>>>(cond, emb_cond, bih_N, bhh_N, bih_D, bhh_D,
                                     ce, biasN, biasD);
  gather_kernel<<<4096, 256, 0, stream>>>(emb_N, input_word, Xe, 0);
  gather_kernel<<<4096, 256, 0, stream>>>(emb_D, input_word, Xd, 1);
  init_enc<<<256, 256, 0, stream>>>(ce, hb, cbuf);

  // encoder precompute + recurrence (per-step launches: coherent by construction)
  gemm_bt_kernel<false><<<dim3(32, 32), 256, 0, stream>>>(Xe, wihN, Xp, biasN, 4096, 1024);
  for (int t = 0; t < 64; ++t) {
    u16* hcur = hb + (size_t)(t & 1) * 65536;
    u16* hnxt = hb + (size_t)((t + 1) & 1) * 65536;
    lstm_step2<<<256, 256, 0, stream>>>(hcur, whhN, Xp, cbuf, hnxt, nullptr,
                                        (t == 63) ? hf : nullptr, t);
  }
  // latent + decoder h0 (writes hb[0] and re-zeroes cell state)
  latent_hd0_kernel<<<64, 256, 0, stream>>>(hf, W_mean, b_mean, W_logvar, b_logvar,
                                            W_st, b_st, eps, ce, hb, cbuf);
  // decoder precompute + recurrence
  gemm_bt_kernel<false><<<dim3(32, 32), 256, 0, stream>>>(Xd, wihD, Xp, biasD, 4096, 1024);
  for (int t = 0; t < 64; ++t) {
    u16* hcur = hb + (size_t)(t & 1) * 65536;
    u16* hnxt = hb + (size_t)((t + 1) & 1) * 65536;
    lstm_step2<<<256, 256, 0, stream>>>(hcur, whhD, Xp, cbuf, hnxt,
                                        hsd + (size_t)t * 65536, nullptr, t);
  }
  // logits = hs_d @ W_out^T + b_out, remapped [t,b,:] -> [b,t,:], NT stores
  gemm_bt_kernel<true><<<dim3(250, 32), 256, 0, stream>>>(hsd, wout, out, b_out, 32000, 1024);
}

// Round 6
// 1583.130 us; speedup vs baseline: 2.2527x; 1.2243x over previous
//
#include <hip/hip_runtime.h>
#include <hip/hip_bf16.h>

typedef unsigned short u16;
typedef unsigned int   u32;
typedef __attribute__((ext_vector_type(8))) short short8;   // 8 x bf16 (4 VGPRs)
typedef __attribute__((ext_vector_type(4))) float f32x4;

#define DEVINL static __device__ __forceinline__

// round-to-nearest-even f32 -> bf16
DEVINL u16 f2bf(float x) {
  u32 u = __float_as_uint(x);
  u32 r = (u + 0x7fffu + ((u >> 16) & 1u)) >> 16;
  return (u16)r;
}

// async global->LDS, 16B per lane. LDS dest = uniform base + lane*16.
#define GLD16(gp, lp) __builtin_amdgcn_global_load_lds(                     \
    (const __attribute__((address_space(1))) u32*)(gp),                     \
    (__attribute__((address_space(3))) u32*)(lp), 16, 0, 0)

// ---------------------------------------------------------------------------
// fp32 -> bf16 bulk convert (n4 = n/4 float4 chunks)
__global__ __launch_bounds__(256) void conv_kernel(const float* __restrict__ s,
                                                   u16* __restrict__ d, int n4) {
  int i = blockIdx.x * 256 + threadIdx.x;
  if (i < n4) {
    float4 v = ((const float4*)s)[i];
    ushort4 o;
    o.x = f2bf(v.x); o.y = f2bf(v.y); o.z = f2bf(v.z); o.w = f2bf(v.w);
    ((ushort4*)d)[i] = o;
  }
}

// cond_e gather + fused bias vectors (bih+bhh)
__global__ __launch_bounds__(256) void prep_small(
    const int* __restrict__ cond, const float* __restrict__ emb_cond,
    const float* __restrict__ bihN, const float* __restrict__ bhhN,
    const float* __restrict__ bihD, const float* __restrict__ bhhD,
    float* __restrict__ ce, float* __restrict__ biasN, float* __restrict__ biasD) {
  int tid = blockIdx.x * 256 + threadIdx.x;
  if (tid < 512) {
    int b = tid >> 3, j = tid & 7;
    ce[tid] = emb_cond[cond[b] * 8 + j];
  }
  int i = tid - 512;
  if (i >= 0 && i < 4096) {
    biasN[i] = bihN[i] + bhhN[i];
    biasD[i] = bihD[i] + bhhD[i];
  }
}

// encoder h0 = [zeros(B,1016), cond_e] -> bf16 into hbuf[0]; c0 = 0
__global__ __launch_bounds__(256) void init_enc(const float* __restrict__ ce,
                                                u16* __restrict__ hb0,
                                                float* __restrict__ c) {
  int tid = blockIdx.x * 256 + threadIdx.x;   // 64*1024
  int b = tid >> 10, col = tid & 1023;
  float v = (col >= 1016) ? ce[b * 8 + (col - 1016)] : 0.f;
  hb0[tid] = f2bf(v);
  c[tid] = 0.f;
}

// embedding row gather -> bf16, X[t*64+b][1024]
__global__ __launch_bounds__(256) void gather_kernel(const float* __restrict__ emb,
                                                     const int* __restrict__ words,
                                                     u16* __restrict__ X, int dec) {
  int r = blockIdx.x;                    // r = t*64 + b
  int t = r >> 6, b = r & 63;
  int tok = dec ? ((t == 0) ? 0 : words[b * 64 + t - 1]) : words[b * 64 + t];
  float4 v = ((const float4*)(emb + (size_t)tok * 1024))[threadIdx.x];
  ushort4 o;
  o.x = f2bf(v.x); o.y = f2bf(v.y); o.z = f2bf(v.z); o.w = f2bf(v.w);
  ((ushort4*)(X + (size_t)r * 1024))[threadIdx.x] = o;
}

// ---------------------------------------------------------------------------
// C = A(MxK) * B(NxK)^T + bias, bf16 in, fp32 out. 128x128 tile, BK=32.
// Bijective XCD swizzle (requires nwg % 8 == 0). NT: nontemporal C stores
// (512MB logits stream must not evict L3-resident W_out).
template <bool NT>
__global__ __launch_bounds__(256) void gemm_bt_kernel(
    const u16* __restrict__ A, const u16* __restrict__ B,
    float* __restrict__ C, const float* __restrict__ bias, int N, int K) {
  __shared__ u16 lA[128 * 32];
  __shared__ u16 lB[128 * 32];
  const int tid = threadIdx.x;
  const int lane = tid & 63;
  const int wid = tid >> 6;

  // XCD-aware remap: consecutive tiles land on one XCD
  const int nx = gridDim.x, nwg = nx * gridDim.y;
  const int orig = blockIdx.y * nx + blockIdx.x;
  const int wgid = (orig & 7) * (nwg >> 3) + (orig >> 3);
  const int tile_m = (wgid / nx) * 128;
  const int tile_n = (wgid % nx) * 128;
  const int wm = wid >> 1, wn = wid & 1;

  const int ldr = lane >> 2;
  const int lko = (lane & 3) * 8;

  f32x4 acc[4][4];
#pragma unroll
  for (int i = 0; i < 4; ++i)
#pragma unroll
    for (int j = 0; j < 4; ++j) acc[i][j] = (f32x4)0.f;

  const size_t aBase = (size_t)tile_m * K;
  const size_t bBase = (size_t)tile_n * K;

  for (int k0 = 0; k0 < K; k0 += 32) {
    __syncthreads();
#pragma unroll
    for (int q = 0; q < 2; ++q) {
      int ch = wid * 2 + q;
      int row = ch * 16 + ldr;
      GLD16(A + aBase + (size_t)row * K + k0 + lko, &lA[ch * 512]);
      GLD16(B + bBase + (size_t)row * K + k0 + lko, &lB[ch * 512]);
    }
    __syncthreads();
    short8 af[4], bf[4];
#pragma unroll
    for (int i = 0; i < 4; ++i)
      af[i] = *(const short8*)&lA[(wm * 64 + i * 16 + (lane & 15)) * 32 + (lane >> 4) * 8];
#pragma unroll
    for (int j = 0; j < 4; ++j)
      bf[j] = *(const short8*)&lB[(wn * 64 + j * 16 + (lane & 15)) * 32 + (lane >> 4) * 8];
#pragma unroll
    for (int i = 0; i < 4; ++i)
#pragma unroll
      for (int j = 0; j < 4; ++j)
        acc[i][j] = __builtin_amdgcn_mfma_f32_16x16x32_bf16(af[i], bf[j], acc[i][j], 0, 0, 0);
  }

#pragma unroll
  for (int i = 0; i < 4; ++i) {
    int row0 = tile_m + wm * 64 + i * 16 + ((lane >> 4) << 2);
#pragma unroll
    for (int j = 0; j < 4; ++j) {
      int col = tile_n + wn * 64 + j * 16 + (lane & 15);
      float bv = bias[col];
#pragma unroll
      for (int e = 0; e < 4; ++e) {
        size_t o = (size_t)(row0 + e) * (size_t)N + col;
        float v = acc[i][j][e] + bv;
        if (NT) __builtin_nontemporal_store(v, &C[o]);
        else    C[o] = v;
      }
    }
  }
}

// ---------------------------------------------------------------------------
// One LSTM step, 256 WGs (64 col-groups x 4 batch-groups) x 256 threads.
// WG (cg,bg): h-cols [cg*16,cg*16+16), batches [bg*16,bg*16+16). Wave = gate.
// A (16x1024 h-block) staged ONCE per WG into XOR-swizzled LDS via GLD16
// (pre-swizzled source, linear dest); B (Whh) bulk-preloaded into 32 short8
// regs before the barrier -> one bulk latency wait, then MFMAs run from
// regs+LDS. hsd written in [b*64+t] row order (makes logits GEMM C-write
// contiguous). Cross-step coherence via kernel boundaries (proven).
__global__ __launch_bounds__(256) void lstm_step2(
    const u16* __restrict__ hb,    // h_t bf16 [64][1024]
    const u16* __restrict__ Whh,   // bf16 [4096][1024]
    const float* __restrict__ Xp,  // fp32 [4096][4096] (x@Wih^T + bih + bhh)
    float* __restrict__ c,         // fp32 [64][1024], in-place
    u16* __restrict__ hb_n,        // h_{t+1} bf16
    u16* __restrict__ hs_out,      // decoder: hsd base ([b*64+t] order), else null
    float* __restrict__ hT_out,    // encoder t==63: fp32 h_T, else null
    int t) {
  __shared__ __align__(16) char smemA[32768];   // 16 rows x 2048B, XOR-swizzled
  __shared__ float lg[4][16][16];               // [gate][batch][col]
  const int tid = threadIdx.x;
  const int lane = tid & 63;
  const int wid = tid >> 6;        // gate
  const int cg = blockIdx.x >> 2;
  const int bg = blockIdx.x & 3;
  const int hc0 = cg * 16;
  const int b0 = bg * 16;
  const int l15 = lane & 15;
  const int g4 = lane >> 4;
  const int kof = g4 * 8;

  // ---- epilogue indices + Xp prefetch (loads issue now, used at the end)
  const int bb = tid >> 4, n = tid & 15;
  const int b = b0 + bb, col = hc0 + n;
  const size_t xrow = (size_t)(t * 64 + b) * 4096 + col;
  const float xg0 = Xp[xrow];
  const float xg1 = Xp[xrow + 1024];
  const float xg2 = Xp[xrow + 2048];
  const float xg3 = Xp[xrow + 3072];

  // ---- stage A block -> LDS, inverse-swizzled source, linear dest
  const char* hbase = (const char*)(hb + (size_t)b0 * 1024);
#pragma unroll
  for (int q = 0; q < 8; ++q) {
    int o = q * 4096 + wid * 1024 + lane * 16;     // linear LDS byte offset
    int row = o >> 11;                              // 0..15
    int cb = o & 2047;
    const char* src = hbase + row * 2048 + (cb ^ ((row & 7) << 4));
    GLD16(src, smemA + q * 4096 + wid * 1024);
  }

  // ---- bulk-preload B fragments (this wave's gate, 16 cols, full K)
  const u16* Brow = Whh + (size_t)(wid * 1024 + hc0 + l15) * 1024 + kof;
  short8 breg[32];
#pragma unroll
  for (int kk = 0; kk < 32; ++kk)
    breg[kk] = *(const short8*)(Brow + kk * 32);

  __syncthreads();   // drains GLD16 + breg loads; A now in LDS

  // ---- 32 MFMAs, 4 independent chains, A from swizzled LDS
  f32x4 acc[4];
#pragma unroll
  for (int i = 0; i < 4; ++i) acc[i] = (f32x4)0.f;
#pragma unroll
  for (int kk = 0; kk < 32; ++kk) {
    int cb = kk * 64 + g4 * 16;
    const short8 a = *(const short8*)(smemA + l15 * 2048 + (cb ^ ((l15 & 7) << 4)));
    acc[kk & 3] = __builtin_amdgcn_mfma_f32_16x16x32_bf16(a, breg[kk], acc[kk & 3], 0, 0, 0);
  }
  f32x4 asum = acc[0] + acc[1] + acc[2] + acc[3];
  {
    int m = g4 * 4;
#pragma unroll
    for (int e = 0; e < 4; ++e) lg[wid][m + e][l15] = asum[e];
  }
  __syncthreads();

  // ---- cell update: 1 cell per thread
  float gi = lg[0][bb][n] + xg0;
  float gf = lg[1][bb][n] + xg1;
  float gg = lg[2][bb][n] + xg2;
  float go = lg[3][bb][n] + xg3;
  float si = 1.f / (1.f + __expf(-gi));
  float sf = 1.f / (1.f + __expf(-gf));
  float so = 1.f / (1.f + __expf(-go));
  float tg = tanhf(gg);
  int ci = b * 1024 + col;
  float cn = sf * c[ci] + si * tg;
  float hn = so * tanhf(cn);
  c[ci] = cn;
  u16 h16 = f2bf(hn);
  hb_n[ci] = h16;
  if (hs_out) hs_out[((size_t)b * 64 + t) * 1024 + col] = h16;
  if (hT_out) hT_out[ci] = hn;
}

// ---------------------------------------------------------------------------
// mean/logvar/latent + hd0 = [latent|cond_e] @ W_st^T + b_st -> bf16 h0; c=0.
__global__ __launch_bounds__(256) void latent_hd0_kernel(
    const float* hT, const float* Wm, const float* bm,
    const float* Wl, const float* bl, const float* Wst, const float* bst,
    const float* eps, const float* ce, u16* hb0, float* c) {
  __shared__ float red[64][4];
  __shared__ float ml[64];
  __shared__ float lat[40];
  int b = blockIdx.x;
  int tid = threadIdx.x;
  int o = tid >> 2, p = tid & 3;
  const float* w = (o < 32) ? (Wm + (size_t)o * 1024) : (Wl + (size_t)(o - 32) * 1024);
  const float* h = hT + (size_t)b * 1024;
  float s = 0.f;
  for (int k = p * 256; k < p * 256 + 256; ++k) s += h[k] * w[k];
  red[o][p] = s;
  __syncthreads();
  if (tid < 64) {
    float v = red[tid][0] + red[tid][1] + red[tid][2] + red[tid][3];
    v += (tid < 32) ? bm[tid] : bl[tid - 32];
    ml[tid] = v;
  }
  __syncthreads();
  if (tid < 32) lat[tid] = eps[b * 32 + tid] * __expf(0.5f * ml[32 + tid]) + ml[tid];
  if (tid >= 32 && tid < 40) lat[tid] = ce[b * 8 + (tid - 32)];
  __syncthreads();
  for (int hc = tid; hc < 1024; hc += 256) {
    float s2 = bst[hc];
    const float* wr = Wst + (size_t)hc * 40;
#pragma unroll
    for (int j = 0; j < 40; ++j) s2 += lat[j] * wr[j];
    int i = b * 1024 + hc;
    hb0[i] = f2bf(s2);
    c[i] = 0.f;
  }
}

// ---------------------------------------------------------------------------
extern "C" void kernel_launch(void* const* d_in, const int* in_sizes, int n_in,
                              void* d_out, int out_size, void* d_ws, size_t ws_size,
                              hipStream_t stream) {
  const int*   input_word = (const int*)d_in[0];
  const int*   cond       = (const int*)d_in[1];
  const float* emb_N      = (const float*)d_in[2];
  const float* Wih_N      = (const float*)d_in[3];
  const float* Whh_N      = (const float*)d_in[4];
  const float* bih_N      = (const float*)d_in[5];
  const float* bhh_N      = (const float*)d_in[6];
  const float* emb_D      = (const float*)d_in[7];
  const float* Wih_D      = (const float*)d_in[8];
  const float* Whh_D      = (const float*)d_in[9];
  const float* bih_D      = (const float*)d_in[10];
  const float* bhh_D      = (const float*)d_in[11];
  const float* emb_cond   = (const float*)d_in[12];
  const float* W_mean     = (const float*)d_in[13];
  const float* b_mean     = (const float*)d_in[14];
  const float* W_logvar   = (const float*)d_in[15];
  const float* b_logvar   = (const float*)d_in[16];
  const float* W_st       = (const float*)d_in[17];
  const float* b_st       = (const float*)d_in[18];
  const float* W_out      = (const float*)d_in[19];
  const float* b_out      = (const float*)d_in[20];
  const float* eps        = (const float*)d_in[21];
  float* out = (float*)d_out;

  char* ws = (char*)d_ws;
  size_t off = 0;
  auto alloc = [&](size_t b) { size_t p = off; off += (b + 255) & ~(size_t)255; return p; };
  u16*   wihN = (u16*)(ws + alloc(4096ull * 1024 * 2));
  u16*   whhN = (u16*)(ws + alloc(4096ull * 1024 * 2));
  u16*   wihD = (u16*)(ws + alloc(4096ull * 1024 * 2));
  u16*   whhD = (u16*)(ws + alloc(4096ull * 1024 * 2));
  u16*   wout = (u16*)(ws + alloc(32000ull * 1024 * 2));
  u16*   Xe   = (u16*)(ws + alloc(4096ull * 1024 * 2));
  u16*   Xd   = (u16*)(ws + alloc(4096ull * 1024 * 2));
  float* Xp   = (float*)(ws + alloc(4096ull * 4096 * 4));   // enc then dec
  u16*   hsd  = (u16*)(ws + alloc(4096ull * 1024 * 2));     // [b*64+t][1024]
  u16*   hb   = (u16*)(ws + alloc(2ull * 64 * 1024 * 2));   // bf16 h dbuf
  float* hf   = (float*)(ws + alloc(64ull * 1024 * 4));     // fp32 h_T (encoder)
  float* cbuf = (float*)(ws + alloc(64ull * 1024 * 4));     // fp32 cell state
  float* biasN = (float*)(ws + alloc(4096 * 4));
  float* biasD = (float*)(ws + alloc(4096 * 4));
  float* ce    = (float*)(ws + alloc(64 * 8 * 4));
  if (off > ws_size) return;

  conv_kernel<<<4096, 256, 0, stream>>>(Wih_N, wihN, 1048576);
  conv_kernel<<<4096, 256, 0, stream>>>(Whh_N, whhN, 1048576);
  conv_kernel<<<4096, 256, 0, stream>>>(Wih_D, wihD, 1048576);
  conv_kernel<<<4096, 256, 0, stream>>>(Whh_D, whhD, 1048576);
  conv_kernel<<<32000, 256, 0, stream>>>(W_out, wout, 8192000);
  prep_small<<<18, 256, 0, stream>>>(cond, emb_cond, bih_N, bhh_N, bih_D, bhh_D,
                                     ce, biasN, biasD);
  gather_kernel<<<4096, 256, 0, stream>>>(emb_N, input_word, Xe, 0);
  gather_kernel<<<4096, 256, 0, stream>>>(emb_D, input_word, Xd, 1);
  init_enc<<<256, 256, 0, stream>>>(ce, hb, cbuf);

  // encoder precompute + recurrence
  gemm_bt_kernel<false><<<dim3(32, 32), 256, 0, stream>>>(Xe, wihN, Xp, biasN, 4096, 1024);
  for (int t = 0; t < 64; ++t) {
    u16* hcur = hb + (size_t)(t & 1) * 65536;
    u16* hnxt = hb + (size_t)((t + 1) & 1) * 65536;
    lstm_step2<<<256, 256, 0, stream>>>(hcur, whhN, Xp, cbuf, hnxt, nullptr,
                                        (t == 63) ? hf : nullptr, t);
  }
  // latent + decoder h0 (writes hb[0] and re-zeroes cell state)
  latent_hd0_kernel<<<64, 256, 0, stream>>>(hf, W_mean, b_mean, W_logvar, b_logvar,
                                            W_st, b_st, eps, ce, hb, cbuf);
  // decoder precompute + recurrence
  gemm_bt_kernel<false><<<dim3(32, 32), 256, 0, stream>>>(Xd, wihD, Xp, biasD, 4096, 1024);
  for (int t = 0; t < 64; ++t) {
    u16* hcur = hb + (size_t)(t & 1) * 65536;
    u16* hnxt = hb + (size_t)((t + 1) & 1) * 65536;
    lstm_step2<<<256, 256, 0, stream>>>(hcur, whhD, Xp, cbuf, hnxt, hsd, nullptr, t);
  }
  // logits[b][t][:] = hsd[b*64+t] @ W_out^T + b_out (contiguous NT stores)
  gemm_bt_kernel<true><<<dim3(250, 32), 256, 0, stream>>>(hsd, wout, out, b_out, 32000, 1024);
}